// Round 4
// baseline (616.540 us; speedup 1.0000x reference)
//
#include <hip/hip_runtime.h>
#include <cstddef>

static constexpr int CB = 64;    // batch
static constexpr int CN = 512;   // nodes
static constexpr int CD = 256;   // node model dim
static constexpr int CE = 128;   // edge model dim
static constexpr int CIT = 20;   // sinkhorn iterations

typedef _Float16 half_t;
typedef __attribute__((ext_vector_type(8))) _Float16 v8h;
typedef __attribute__((ext_vector_type(4))) _Float16 v4h;
typedef __attribute__((ext_vector_type(4))) float v4f;

// ---------------------------------------------------------------------------
// k0: block 0 = mask layout detect; block 1 = zero barrier counters;
// blocks 2..9 = W_a -> fp16 B-fragments (w_aff folded); blocks 10..17 = W_b.
// Fragment layout (B-operand of mfma_f32_16x16x32_f16), same convention the
// R2/R3 fused kernel verified on HW: frag fB = n*8+kf, lane l holds
// W[k = kf*32 + (l>>4)*8 + j][col = n*16 + (l&15)], j = 0..7.
// flag: 0=int32, 1=uint8(bool), 2=float32, 3=int64
// ---------------------------------------------------------------------------
__global__ __launch_bounds__(512) void k0_init(
    const void* __restrict__ mask, int* __restrict__ bar, int* __restrict__ flag,
    const float* __restrict__ W_a, const float* __restrict__ W_b,
    const float* __restrict__ w_aff,
    half_t* __restrict__ WaF, half_t* __restrict__ WbF) {
  const int tid = threadIdx.x;
  const int blk = blockIdx.x;
  if (blk == 1) {
#pragma unroll
    for (int k = 0; k < 4; ++k) bar[tid * 4 + k] = 0;
    return;
  }
  if (blk >= 2) {
    const bool is_a = (blk < 10);
    const float* W = is_a ? W_a : W_b;
    half_t* WF = is_a ? WaF : WbF;
    const int e = (blk - (is_a ? 2 : 10)) * 512 + tid;   // 0..4095
    const int fB = e >> 6, lane = e & 63;
    const int nn = fB >> 3, kf = fB & 7;
    const int col = nn * 16 + (lane & 15);
    const int q = lane >> 4;
    const float scale = is_a ? w_aff[col] : 1.0f;
    v8h hv;
#pragma unroll
    for (int j = 0; j < 8; ++j) {
      const int k = kf * 32 + q * 8 + j;
      hv[j] = (half_t)(W[(size_t)k * CE + col] * scale);
    }
    *(v8h*)&WF[(size_t)e * 8] = hv;
    return;
  }
  // blk == 0: mask dtype detection over first 32768 bytes
  __shared__ int cnt[5];
  if (tid < 5) cnt[tid] = 0;
  __syncthreads();
  const unsigned char* p = (const unsigned char*)mask;
  int l0 = 0, l1 = 0, l2 = 0, l3 = 0, l4 = 0;
  const int base = tid * 64;
  for (int k = 0; k < 64; ++k) {
    const int off = base + k;
    if (p[off]) {
      const int m4 = off & 3;
      if (m4 == 1) l1++;
      else if (m4 == 2) l2++;
      else if (m4 == 3) l3++;
      else if ((off & 7) == 4) l4++;
      else l0++;
    }
  }
  if (l0) atomicAdd(&cnt[0], 1);
  if (l1) atomicAdd(&cnt[1], 1);
  if (l2) atomicAdd(&cnt[2], 1);
  if (l3) atomicAdd(&cnt[3], 1);
  if (l4) atomicAdd(&cnt[4], 1);
  __syncthreads();
  if (tid == 0) {
    int f;
    if (cnt[1]) f = 1;
    else if (cnt[2] || cnt[3]) f = 2;
    else if (cnt[4]) f = 0;
    else if (cnt[0]) f = 3;
    else f = 1;
    *flag = f;
  }
}

// ---------------------------------------------------------------------------
// prep_mfma: out[row, col] fp16 row-major, M=32768, Ncols=128, K=256.
// MODE 0: x = out_emb + pos, W = WaF (w_aff pre-folded)
// MODE 1: x = mask ? pad : in_emb, W = WbF
// Block: 256 thr / 4 waves, 128 rows, full N and K. X staged once into LDS as
// fp16 A-fragments (64 KB); W fragments read straight from global (L2-hot).
// ---------------------------------------------------------------------------
template <int MODE>
__global__ __launch_bounds__(256) void prep_mfma(
    const float* __restrict__ X, const float* __restrict__ extra,
    const void* __restrict__ maskp, const int* __restrict__ flagp,
    const half_t* __restrict__ Wfrag, half_t* __restrict__ out) {
  __shared__ half_t Als[64 * 64 * 8];   // 64 KB: frag fA=(m*8+kf), lane, 8 halves
  const int tid = threadIdx.x;
  const int row0 = blockIdx.x * 128;
  const int flag = (MODE == 1) ? *flagp : 0;

  // ---- stage X: thread t owns row r = t>>1, k-half h = t&1 (128 k) ----
  {
    const int r = tid >> 1, h = tid & 1;
    const int row = row0 + r;
    const int m = r >> 4, l15 = r & 15;
    bool msk = false;
    if (MODE == 1) {
      if (flag == 1)      msk = ((const unsigned char*)maskp)[row] != 0;
      else if (flag == 2) msk = ((const float*)maskp)[row] != 0.0f;
      else if (flag == 3) msk = ((const long long*)maskp)[row] != 0;
      else                msk = ((const int*)maskp)[row] != 0;
    }
    const int i = row & (CN - 1);   // pos row
#pragma unroll
    for (int kk = 0; kk < 4; ++kk) {
      const int kf = h * 4 + kk;
#pragma unroll
      for (int q2 = 0; q2 < 4; ++q2) {
        const int k = kf * 32 + q2 * 8;
        float4 x0, x1;
        if (MODE == 0) {
          x0 = *(const float4*)&X[(size_t)row * CD + k];
          x1 = *(const float4*)&X[(size_t)row * CD + k + 4];
          const float4 p0 = *(const float4*)&extra[(size_t)i * CD + k];
          const float4 p1 = *(const float4*)&extra[(size_t)i * CD + k + 4];
          x0.x += p0.x; x0.y += p0.y; x0.z += p0.z; x0.w += p0.w;
          x1.x += p1.x; x1.y += p1.y; x1.z += p1.z; x1.w += p1.w;
        } else {
          if (msk) {
            x0 = *(const float4*)&extra[k];
            x1 = *(const float4*)&extra[k + 4];
          } else {
            x0 = *(const float4*)&X[(size_t)row * CD + k];
            x1 = *(const float4*)&X[(size_t)row * CD + k + 4];
          }
        }
        v8h hv;
        hv[0] = (half_t)x0.x; hv[1] = (half_t)x0.y;
        hv[2] = (half_t)x0.z; hv[3] = (half_t)x0.w;
        hv[4] = (half_t)x1.x; hv[5] = (half_t)x1.y;
        hv[6] = (half_t)x1.z; hv[7] = (half_t)x1.w;
        *(v8h*)&Als[(size_t)(((m * 8 + kf) * 64) + q2 * 16 + l15) * 8] = hv;
      }
    }
  }
  __syncthreads();

  // ---- MFMA: wave wv owns m-tiles {2wv, 2wv+1} ----
  const int wv = tid >> 6, ln = tid & 63;
  v8h af[2][8];
#pragma unroll
  for (int m2 = 0; m2 < 2; ++m2)
#pragma unroll
    for (int kf = 0; kf < 8; ++kf)
      af[m2][kf] = *(v8h*)&Als[(size_t)((((wv * 2 + m2) * 8 + kf) * 64) + ln) * 8];
  v4f acc[2][8] = {};
#pragma unroll
  for (int nn = 0; nn < 8; ++nn) {
    v8h bf[8];
#pragma unroll
    for (int kf = 0; kf < 8; ++kf)
      bf[kf] = *(const v8h*)&Wfrag[(size_t)((nn * 8 + kf) * 64 + ln) * 8];
#pragma unroll
    for (int m2 = 0; m2 < 2; ++m2)
#pragma unroll
      for (int kf = 0; kf < 8; ++kf)
        acc[m2][nn] = __builtin_amdgcn_mfma_f32_16x16x32_f16(af[m2][kf], bf[kf], acc[m2][nn], 0, 0, 0);
  }
  // ---- epilogue: C-frag (row = mt*16 + q*4 + g, col = nn*16 + l) ----
  const int q = ln >> 4, l = ln & 15;
#pragma unroll
  for (int m2 = 0; m2 < 2; ++m2)
#pragma unroll
    for (int nn = 0; nn < 8; ++nn)
#pragma unroll
      for (int g = 0; g < 4; ++g) {
        const int row = row0 + (wv * 2 + m2) * 16 + q * 4 + g;
        out[(size_t)row * CE + nn * 16 + l] = (half_t)acc[m2][nn][g];
      }
}

// ---------------------------------------------------------------------------
// Per-batch barrier among the 8 slab-blocks of a batch (grid = 512 = 2/CU,
// capacity == grid so all blocks resident).
// ---------------------------------------------------------------------------
__device__ __forceinline__ void batch_barrier(int* __restrict__ bar, int b, int target) {
  __syncthreads();
  if (threadIdx.x == 0) {
    __hip_atomic_fetch_add(&bar[b * 32], 1, __ATOMIC_RELEASE, __HIP_MEMORY_SCOPE_AGENT);
    while (__hip_atomic_load(&bar[b * 32], __ATOMIC_ACQUIRE, __HIP_MEMORY_SCOPE_AGENT) < target)
      __builtin_amdgcn_s_sleep(2);
  }
  __syncthreads();
}

// ---------------------------------------------------------------------------
// fused_reg: block = (batch b, 64-row slab), 256 threads = 4 waves, 2 blocks/CU.
// blockIdx mapping keeps a batch's 8 slabs on one XCD (n mod 8 fixed) while
// the two blocks sharing a CU (n, n+256) serve batches 32 apart, so their
// barrier stalls interleave with each other's compute.
// E slab in registers as packed fp16 in MFMA C-fragment layout (eh[32] v4h):
//   eh[ct][g] <-> E[row = wv*16 + q*4 + g][col = ct*16 + l].
// Stored value exp(aff + b_aff - ln16): the 2^-4 scale cancels in both
// normalizations; keeps fp16 in range.
// ---------------------------------------------------------------------------
__global__ __launch_bounds__(256, 2) void fused_reg(
    const half_t* __restrict__ A_h, const half_t* __restrict__ B_h,
    const float* __restrict__ baff, float* __restrict__ P,
    float* __restrict__ part, int* __restrict__ bar) {
  __shared__ float comb[4][2][512];      // 16 KB
  __shared__ float2 w12[512];            // {0.5*v*csinv, v}
  __shared__ float csinv_l[512];
  __shared__ float rinv_l[64];

  const int tid = threadIdx.x;
  const int wv = tid >> 6, ln = tid & 63;
  const int q = ln >> 4, l = ln & 15;
  const int n = blockIdx.x;
  const int slab = (n >> 3) & 7;
  const int b = (n & 7) | ((n >> 6) << 3);
  const int i0 = slab * 64;
  const float bbs = *baff - 2.7725887f;   // fold 2^-4 scale into exp

  // ---- GEMM: 16 rows x 512 cols per wave, K=128, fp16 MFMA + fused init ----
  v8h af[4];
  {
    const half_t* Arow = &A_h[((size_t)b * CN + i0 + wv * 16 + l) * CE];
#pragma unroll
    for (int ki = 0; ki < 4; ++ki)
      af[ki] = *(const v8h*)&Arow[ki * 32 + q * 8];
  }
  v4h eh[32];
  float d[4] = {0.0f, 0.0f, 0.0f, 0.0f};
  const half_t* Bbase = &B_h[(size_t)b * CN * CE];
#pragma unroll
  for (int ct = 0; ct < 32; ++ct) {
    v8h bf[4];
    const half_t* Brow = &Bbase[(size_t)(ct * 16 + l) * CE];
#pragma unroll
    for (int ki = 0; ki < 4; ++ki)
      bf[ki] = *(const v8h*)&Brow[ki * 32 + q * 8];
    v4f acc = {};
#pragma unroll
    for (int ki = 0; ki < 4; ++ki)
      acc = __builtin_amdgcn_mfma_f32_16x16x32_f16(af[ki], bf[ki], acc, 0, 0, 0);
    float colsum = 0.0f;
    v4h ev;
#pragma unroll
    for (int g = 0; g < 4; ++g) {
      const float e = __expf(acc[g] + bbs);
      d[g] += e;
      colsum += e;
      ev[g] = (half_t)e;
    }
    eh[ct] = ev;
    colsum += __shfl_xor(colsum, 16);
    colsum += __shfl_xor(colsum, 32);
    if (ln < 16) comb[wv][0][ct * 16 + ln] = colsum;
  }
#pragma unroll
  for (int g = 0; g < 4; ++g) {
#pragma unroll
    for (int m = 1; m < 16; m <<= 1) d[g] += __shfl_xor(d[g], m);
  }
  if (l == 0) {
#pragma unroll
    for (int g = 0; g < 4; ++g) rinv_l[wv * 16 + q * 4 + g] = 1.0f / d[g];
  }
  __syncthreads();

  // part[slot][b][slab][var][col]
#define PIDX(slot, bb, sl, var, col) \
  ((((((size_t)(slot)*64 + (bb)) * 8 + (sl)) * 2 + (var)) * 512) + (col))

  // ---- init exchange: column sums -> csinv; w init (v = 1) ----
  int gen = 0;
  {
#pragma unroll
    for (int hh = 0; hh < 2; ++hh) {
      const int c = tid + hh * 256;
      float S = comb[0][0][c] + comb[1][0][c] + comb[2][0][c] + comb[3][0][c];
      part[PIDX(0, b, slab, 0, c)] = S;
    }
    ++gen;
    batch_barrier(bar, b, 8 * gen);
#pragma unroll
    for (int hh = 0; hh < 2; ++hh) {
      const int c = tid + hh * 256;
      float T = 0.0f;
#pragma unroll
      for (int sl = 0; sl < 8; ++sl)
        T += __hip_atomic_load(&part[PIDX(0, b, sl, 0, c)],
                               __ATOMIC_RELAXED, __HIP_MEMORY_SCOPE_AGENT);
      const float ci = 1.0f / T;
      csinv_l[c] = ci;
      w12[c] = make_float2(0.5f * ci, 1.0f);
    }
  }
  float rv[4];
#pragma unroll
  for (int g = 0; g < 4; ++g) rv[g] = rinv_l[wv * 16 + q * 4 + g];

  // ---- 20 sinkhorn iterations ----
  float u_[4], uri[4];
  for (int t = 0; t < CIT; ++t) {
    __syncthreads();
    float p1[4] = {0, 0, 0, 0}, p2[4] = {0, 0, 0, 0};
#pragma unroll
    for (int ct = 0; ct < 32; ++ct) {
      const float2 w = w12[ct * 16 + l];
      const v4h ev = eh[ct];
#pragma unroll
      for (int g = 0; g < 4; ++g) {
        const float e = (float)ev[g];
        p1[g] = fmaf(e, w.x, p1[g]);
        p2[g] = fmaf(e, w.y, p2[g]);
      }
    }
#pragma unroll
    for (int g = 0; g < 4; ++g) {
#pragma unroll
      for (int m = 1; m < 16; m <<= 1) {
        p1[g] += __shfl_xor(p1[g], m);
        p2[g] += __shfl_xor(p2[g], m);
      }
      u_[g] = 1.0f / (p1[g] + 0.5f * rv[g] * p2[g]);
      uri[g] = u_[g] * rv[g];
    }
#pragma unroll
    for (int ct = 0; ct < 32; ++ct) {
      const v4h ev = eh[ct];
      float s1 = 0.0f, s2 = 0.0f;
#pragma unroll
      for (int g = 0; g < 4; ++g) {
        const float e = (float)ev[g];
        s1 = fmaf(e, u_[g], s1);
        s2 = fmaf(e, uri[g], s2);
      }
      s1 += __shfl_xor(s1, 16); s1 += __shfl_xor(s1, 32);
      s2 += __shfl_xor(s2, 16); s2 += __shfl_xor(s2, 32);
      if (ln < 16) {
        comb[wv][0][ct * 16 + ln] = s1;
        comb[wv][1][ct * 16 + ln] = s2;
      }
    }
    __syncthreads();
    const int slot = gen & 1;
#pragma unroll
    for (int hh = 0; hh < 2; ++hh) {
      const int c = tid + hh * 256;
      const float S1 = comb[0][0][c] + comb[1][0][c] + comb[2][0][c] + comb[3][0][c];
      const float S2 = comb[0][1][c] + comb[1][1][c] + comb[2][1][c] + comb[3][1][c];
      part[PIDX(slot, b, slab, 0, c)] = S1;
      part[PIDX(slot, b, slab, 1, c)] = S2;
    }
    ++gen;
    batch_barrier(bar, b, 8 * gen);
#pragma unroll
    for (int hh = 0; hh < 2; ++hh) {
      const int c = tid + hh * 256;
      float T1 = 0.0f, T2 = 0.0f;
#pragma unroll
      for (int sl = 0; sl < 8; ++sl) {
        T1 += __hip_atomic_load(&part[PIDX(slot, b, sl, 0, c)],
                                __ATOMIC_RELAXED, __HIP_MEMORY_SCOPE_AGENT);
        T2 += __hip_atomic_load(&part[PIDX(slot, b, sl, 1, c)],
                                __ATOMIC_RELAXED, __HIP_MEMORY_SCOPE_AGENT);
      }
      const float ci = csinv_l[c];
      const float vv = 1.0f / (0.5f * fmaf(ci, T1, T2));
      w12[c] = make_float2(0.5f * vv * ci, vv);
    }
  }

  // ---- finalize: P = E * u_i * v_j * (0.5*csinv_j + 0.5*rinv_i) ----
  __syncthreads();
  float* Pb = &P[((size_t)b * CN + i0 + wv * 16 + q * 4) * CN];
#pragma unroll
  for (int ct = 0; ct < 32; ++ct) {
    const float2 w = w12[ct * 16 + l];
    const float c1 = w.x;
    const float c2 = 0.5f * w.y;
    const v4h ev = eh[ct];
#pragma unroll
    for (int g = 0; g < 4; ++g) {
      const float e = (float)ev[g];
      Pb[(size_t)g * CN + ct * 16 + l] = e * fmaf(u_[g], c1, uri[g] * c2);
    }
  }
#undef PIDX
}

// ---------------------------------------------------------------------------
extern "C" void kernel_launch(void* const* d_in, const int* in_sizes, int n_in,
                              void* d_out, int out_size, void* d_ws, size_t ws_size,
                              hipStream_t stream) {
  const float* in_emb  = (const float*)d_in[0];
  const void*  mask    = d_in[1];
  const float* out_emb = (const float*)d_in[2];
  const float* pad     = (const float*)d_in[3];
  const float* pos     = (const float*)d_in[4];
  const float* W_a     = (const float*)d_in[5];
  const float* W_b     = (const float*)d_in[6];
  const float* w_aff   = (const float*)d_in[7];
  const float* b_aff   = (const float*)d_in[8];
  float* P = (float*)d_out;

  char* ws = (char*)d_ws;
  const size_t MB = 1024 * 1024;
  half_t* A_h  = (half_t*)ws;                         // 8 MB
  half_t* Bm_h = (half_t*)(ws + 8 * MB);              // 8 MB
  float*  part = (float*)(ws + 16 * MB);              // 4 MB
  int*    bar  = (int*)(ws + 20 * MB);                // 8 KB
  int*    flag = (int*)(ws + 20 * MB + 8192);         // 4 B
  half_t* WaF  = (half_t*)(ws + 20 * MB + 12288);     // 64 KB
  half_t* WbF  = (half_t*)(ws + 20 * MB + 12288 + 65536);  // 64 KB

  k0_init<<<dim3(18), dim3(512), 0, stream>>>(mask, bar, flag, W_a, W_b, w_aff, WaF, WbF);
  prep_mfma<0><<<dim3(CB * CN / 128), dim3(256), 0, stream>>>(
      out_emb, pos, nullptr, flag, WaF, A_h);
  prep_mfma<1><<<dim3(CB * CN / 128), dim3(256), 0, stream>>>(
      in_emb, pad, mask, flag, WbF, Bm_h);
  fused_reg<<<dim3(512), dim3(256), 0, stream>>>(A_h, Bm_h, b_aff, P, part, bar);
}

// Round 5
// 323.656 us; speedup vs baseline: 1.9049x; 1.9049x over previous
//
#include <hip/hip_runtime.h>
#include <cstddef>

static constexpr int CB = 64;    // batch
static constexpr int CN = 512;   // nodes
static constexpr int CD = 256;   // node model dim
static constexpr int CE = 128;   // edge model dim
static constexpr int CIT = 20;   // sinkhorn iterations

typedef _Float16 half_t;
typedef __attribute__((ext_vector_type(8))) _Float16 v8h;
typedef __attribute__((ext_vector_type(4))) _Float16 v4h;
typedef __attribute__((ext_vector_type(4))) float v4f;

// ---------------------------------------------------------------------------
// k0: block 0 = mask layout detect; block 1 = zero barrier counters;
// blocks 2..9 = W_a -> fp16 B-fragments (w_aff folded); blocks 10..17 = W_b.
// flag: 0=int32, 1=uint8(bool), 2=float32, 3=int64
// ---------------------------------------------------------------------------
__global__ __launch_bounds__(512) void k0_init(
    const void* __restrict__ mask, int* __restrict__ bar, int* __restrict__ flag,
    const float* __restrict__ W_a, const float* __restrict__ W_b,
    const float* __restrict__ w_aff,
    half_t* __restrict__ WaF, half_t* __restrict__ WbF) {
  const int tid = threadIdx.x;
  const int blk = blockIdx.x;
  if (blk == 1) {
#pragma unroll
    for (int k = 0; k < 4; ++k) bar[tid * 4 + k] = 0;
    return;
  }
  if (blk >= 2) {
    const bool is_a = (blk < 10);
    const float* W = is_a ? W_a : W_b;
    half_t* WF = is_a ? WaF : WbF;
    const int e = (blk - (is_a ? 2 : 10)) * 512 + tid;   // 0..4095
    const int fB = e >> 6, lane = e & 63;
    const int nn = fB >> 3, kf = fB & 7;
    const int col = nn * 16 + (lane & 15);
    const int q = lane >> 4;
    const float scale = is_a ? w_aff[col] : 1.0f;
    v8h hv;
#pragma unroll
    for (int j = 0; j < 8; ++j) {
      const int k = kf * 32 + q * 8 + j;
      hv[j] = (half_t)(W[(size_t)k * CE + col] * scale);
    }
    *(v8h*)&WF[(size_t)e * 8] = hv;
    return;
  }
  // blk == 0: mask dtype detection over first 32768 bytes
  __shared__ int cnt[5];
  if (tid < 5) cnt[tid] = 0;
  __syncthreads();
  const unsigned char* p = (const unsigned char*)mask;
  int l0 = 0, l1 = 0, l2 = 0, l3 = 0, l4 = 0;
  const int base = tid * 64;
  for (int k = 0; k < 64; ++k) {
    const int off = base + k;
    if (p[off]) {
      const int m4 = off & 3;
      if (m4 == 1) l1++;
      else if (m4 == 2) l2++;
      else if (m4 == 3) l3++;
      else if ((off & 7) == 4) l4++;
      else l0++;
    }
  }
  if (l0) atomicAdd(&cnt[0], 1);
  if (l1) atomicAdd(&cnt[1], 1);
  if (l2) atomicAdd(&cnt[2], 1);
  if (l3) atomicAdd(&cnt[3], 1);
  if (l4) atomicAdd(&cnt[4], 1);
  __syncthreads();
  if (tid == 0) {
    int f;
    if (cnt[1]) f = 1;
    else if (cnt[2] || cnt[3]) f = 2;
    else if (cnt[4]) f = 0;
    else if (cnt[0]) f = 3;
    else f = 1;
    *flag = f;
  }
}

// ---------------------------------------------------------------------------
// prep_mfma (validated in R4): out[row, col] fp16 row-major, M=32768, N=128,
// K=256. MODE 0: x = out_emb + pos, W = WaF (w_aff folded).
// MODE 1: x = mask ? pad : in_emb, W = WbF.
// ---------------------------------------------------------------------------
template <int MODE>
__global__ __launch_bounds__(256) void prep_mfma(
    const float* __restrict__ X, const float* __restrict__ extra,
    const void* __restrict__ maskp, const int* __restrict__ flagp,
    const half_t* __restrict__ Wfrag, half_t* __restrict__ out) {
  __shared__ half_t Als[64 * 64 * 8];   // 64 KB
  const int tid = threadIdx.x;
  const int row0 = blockIdx.x * 128;
  const int flag = (MODE == 1) ? *flagp : 0;
  {
    const int r = tid >> 1, h = tid & 1;
    const int row = row0 + r;
    const int m = r >> 4, l15 = r & 15;
    bool msk = false;
    if (MODE == 1) {
      if (flag == 1)      msk = ((const unsigned char*)maskp)[row] != 0;
      else if (flag == 2) msk = ((const float*)maskp)[row] != 0.0f;
      else if (flag == 3) msk = ((const long long*)maskp)[row] != 0;
      else                msk = ((const int*)maskp)[row] != 0;
    }
    const int i = row & (CN - 1);
#pragma unroll
    for (int kk = 0; kk < 4; ++kk) {
      const int kf = h * 4 + kk;
#pragma unroll
      for (int q2 = 0; q2 < 4; ++q2) {
        const int k = kf * 32 + q2 * 8;
        float4 x0, x1;
        if (MODE == 0) {
          x0 = *(const float4*)&X[(size_t)row * CD + k];
          x1 = *(const float4*)&X[(size_t)row * CD + k + 4];
          const float4 p0 = *(const float4*)&extra[(size_t)i * CD + k];
          const float4 p1 = *(const float4*)&extra[(size_t)i * CD + k + 4];
          x0.x += p0.x; x0.y += p0.y; x0.z += p0.z; x0.w += p0.w;
          x1.x += p1.x; x1.y += p1.y; x1.z += p1.z; x1.w += p1.w;
        } else {
          if (msk) {
            x0 = *(const float4*)&extra[k];
            x1 = *(const float4*)&extra[k + 4];
          } else {
            x0 = *(const float4*)&X[(size_t)row * CD + k];
            x1 = *(const float4*)&X[(size_t)row * CD + k + 4];
          }
        }
        v8h hv;
        hv[0] = (half_t)x0.x; hv[1] = (half_t)x0.y;
        hv[2] = (half_t)x0.z; hv[3] = (half_t)x0.w;
        hv[4] = (half_t)x1.x; hv[5] = (half_t)x1.y;
        hv[6] = (half_t)x1.z; hv[7] = (half_t)x1.w;
        *(v8h*)&Als[(size_t)(((m * 8 + kf) * 64) + q2 * 16 + l15) * 8] = hv;
      }
    }
  }
  __syncthreads();
  const int wv = tid >> 6, ln = tid & 63;
  v8h af[2][8];
#pragma unroll
  for (int m2 = 0; m2 < 2; ++m2)
#pragma unroll
    for (int kf = 0; kf < 8; ++kf)
      af[m2][kf] = *(v8h*)&Als[(size_t)((((wv * 2 + m2) * 8 + kf) * 64) + ln) * 8];
  v4f acc[2][8] = {};
#pragma unroll
  for (int nn = 0; nn < 8; ++nn) {
    v8h bf[8];
#pragma unroll
    for (int kf = 0; kf < 8; ++kf)
      bf[kf] = *(const v8h*)&Wfrag[(size_t)((nn * 8 + kf) * 64 + ln) * 8];
#pragma unroll
    for (int m2 = 0; m2 < 2; ++m2)
#pragma unroll
      for (int kf = 0; kf < 8; ++kf)
        acc[m2][nn] = __builtin_amdgcn_mfma_f32_16x16x32_f16(af[m2][kf], bf[kf], acc[m2][nn], 0, 0, 0);
  }
  const int q = ln >> 4, l = ln & 15;
#pragma unroll
  for (int m2 = 0; m2 < 2; ++m2)
#pragma unroll
    for (int nn = 0; nn < 8; ++nn)
#pragma unroll
      for (int g = 0; g < 4; ++g) {
        const int row = row0 + (wv * 2 + m2) * 16 + q * 4 + g;
        out[(size_t)row * CE + nn * 16 + l] = (half_t)acc[m2][nn][g];
      }
}

// ---------------------------------------------------------------------------
// fused_reg (R3 shape): block = (batch b, 128-row slab), 512 thr = 8 waves,
// grid 256 = 1 block/CU. E slab in registers, packed fp16, MFMA C-layout:
//   eh[ct][g] <-> E[row = wv*16 + q*4 + g][col = ct*16 + l].
// exp(aff + b_aff - ln16): 2^-4 scale cancels in both normalizations.
// Cross-slab exchange: RELAXED-only MALL protocol — atomic relaxed agent
// stores for partials, __syncthreads (drains vmcnt on every wave) orders
// them before thread0's relaxed fetch_add arrive; spin is a relaxed load;
// readback is relaxed atomic loads of the 3 REMOTE slabs (own kept in regs).
// No acquire/release -> no L2-wide invalidate/writeback per round.
// ---------------------------------------------------------------------------
__global__ __launch_bounds__(512) void fused_reg(
    const half_t* __restrict__ A_h, const half_t* __restrict__ B_h,
    const float* __restrict__ baff, float* __restrict__ P,
    float* __restrict__ part, int* __restrict__ bar) {
  __shared__ float comb[8][2][512];      // 32 KB
  __shared__ float2 w12[512];            // {0.5*v*csinv, v}
  __shared__ float csinv_l[512];
  __shared__ float rinv_l[128];

  const int tid = threadIdx.x;
  const int wv = tid >> 6, ln = tid & 63;
  const int q = ln >> 4, l = ln & 15;
  const int b = blockIdx.x & 63;
  const int slab = blockIdx.x >> 6;
  const int i0 = slab * 128;
  const float bbs = *baff - 2.7725887f;   // fold 2^-4 scale into exp

  // ---- GEMM: 16 rows x 512 cols per wave, K=128, fp16 MFMA + fused init ----
  v8h af[4];
  {
    const half_t* Arow = &A_h[((size_t)b * CN + i0 + wv * 16 + l) * CE];
#pragma unroll
    for (int ki = 0; ki < 4; ++ki)
      af[ki] = *(const v8h*)&Arow[ki * 32 + q * 8];
  }
  v4h eh[32];
  float d[4] = {0.0f, 0.0f, 0.0f, 0.0f};
  const half_t* Bbase = &B_h[(size_t)b * CN * CE];
#pragma unroll
  for (int ct = 0; ct < 32; ++ct) {
    v8h bf[4];
    const half_t* Brow = &Bbase[(size_t)(ct * 16 + l) * CE];
#pragma unroll
    for (int ki = 0; ki < 4; ++ki)
      bf[ki] = *(const v8h*)&Brow[ki * 32 + q * 8];
    v4f acc = {};
#pragma unroll
    for (int ki = 0; ki < 4; ++ki)
      acc = __builtin_amdgcn_mfma_f32_16x16x32_f16(af[ki], bf[ki], acc, 0, 0, 0);
    float colsum = 0.0f;
    v4h ev;
#pragma unroll
    for (int g = 0; g < 4; ++g) {
      const float e = __expf(acc[g] + bbs);
      d[g] += e;
      colsum += e;
      ev[g] = (half_t)e;
    }
    eh[ct] = ev;
    colsum += __shfl_xor(colsum, 16);
    colsum += __shfl_xor(colsum, 32);
    if (ln < 16) comb[wv][0][ct * 16 + ln] = colsum;
  }
#pragma unroll
  for (int g = 0; g < 4; ++g) {
#pragma unroll
    for (int m = 1; m < 16; m <<= 1) d[g] += __shfl_xor(d[g], m);
  }
  if (l == 0) {
#pragma unroll
    for (int g = 0; g < 4; ++g) rinv_l[wv * 16 + q * 4 + g] = 1.0f / d[g];
  }
  __syncthreads();

  // part[slot][b][slab][var][col]
#define PIDX(slot, bb, sl, var, col) \
  ((((((size_t)(slot)*64 + (bb)) * 4 + (sl)) * 2 + (var)) * 512) + (col))

  int gen = 0;
  // ---- init exchange: column sums -> csinv; w init (v = 1) ----
  {
    float S = 0.0f;
#pragma unroll
    for (int w = 0; w < 8; ++w) S += comb[w][0][tid];
    __hip_atomic_store(&part[PIDX(0, b, slab, 0, tid)], S,
                       __ATOMIC_RELAXED, __HIP_MEMORY_SCOPE_AGENT);
    ++gen;
    __syncthreads();   // drains vmcnt on every wave -> stores at MALL
    if (tid == 0) {
      __hip_atomic_fetch_add(&bar[b * 32], 1, __ATOMIC_RELAXED, __HIP_MEMORY_SCOPE_AGENT);
      while (__hip_atomic_load(&bar[b * 32], __ATOMIC_RELAXED, __HIP_MEMORY_SCOPE_AGENT) < 4 * gen)
        __builtin_amdgcn_s_sleep(2);
    }
    __syncthreads();
    float T = S;
#pragma unroll
    for (int sl = 0; sl < 4; ++sl) {
      if (sl == slab) continue;
      T += __hip_atomic_load(&part[PIDX(0, b, sl, 0, tid)],
                             __ATOMIC_RELAXED, __HIP_MEMORY_SCOPE_AGENT);
    }
    const float ci = 1.0f / T;
    csinv_l[tid] = ci;
    w12[tid] = make_float2(0.5f * ci, 1.0f);
  }
  float rv[4];
#pragma unroll
  for (int g = 0; g < 4; ++g) rv[g] = rinv_l[wv * 16 + q * 4 + g];

  // ---- 20 sinkhorn iterations ----
  float u_[4], uri[4];
  for (int t = 0; t < CIT; ++t) {
    __syncthreads();   // w12 ready
    float p1[4] = {0, 0, 0, 0}, p2[4] = {0, 0, 0, 0};
#pragma unroll
    for (int ct = 0; ct < 32; ++ct) {
      const float2 w = w12[ct * 16 + l];
      const v4h ev = eh[ct];
#pragma unroll
      for (int g = 0; g < 4; ++g) {
        const float e = (float)ev[g];
        p1[g] = fmaf(e, w.x, p1[g]);
        p2[g] = fmaf(e, w.y, p2[g]);
      }
    }
#pragma unroll
    for (int g = 0; g < 4; ++g) {
#pragma unroll
      for (int m = 1; m < 16; m <<= 1) {
        p1[g] += __shfl_xor(p1[g], m);
        p2[g] += __shfl_xor(p2[g], m);
      }
      u_[g] = 1.0f / (p1[g] + 0.5f * rv[g] * p2[g]);
      uri[g] = u_[g] * rv[g];
    }
#pragma unroll
    for (int ct = 0; ct < 32; ++ct) {
      const v4h ev = eh[ct];
      float s1 = 0.0f, s2 = 0.0f;
#pragma unroll
      for (int g = 0; g < 4; ++g) {
        const float e = (float)ev[g];
        s1 = fmaf(e, u_[g], s1);
        s2 = fmaf(e, uri[g], s2);
      }
      s1 += __shfl_xor(s1, 16); s1 += __shfl_xor(s1, 32);
      s2 += __shfl_xor(s2, 16); s2 += __shfl_xor(s2, 32);
      if (ln < 16) {
        comb[wv][0][ct * 16 + ln] = s1;
        comb[wv][1][ct * 16 + ln] = s2;
      }
    }
    __syncthreads();
    const int slot = gen & 1;
    float S1 = 0.0f, S2 = 0.0f;
#pragma unroll
    for (int w = 0; w < 8; ++w) {
      S1 += comb[w][0][tid];
      S2 += comb[w][1][tid];
    }
    __hip_atomic_store(&part[PIDX(slot, b, slab, 0, tid)], S1,
                       __ATOMIC_RELAXED, __HIP_MEMORY_SCOPE_AGENT);
    __hip_atomic_store(&part[PIDX(slot, b, slab, 1, tid)], S2,
                       __ATOMIC_RELAXED, __HIP_MEMORY_SCOPE_AGENT);
    ++gen;
    __syncthreads();   // drains vmcnt on every wave
    if (tid == 0) {
      __hip_atomic_fetch_add(&bar[b * 32], 1, __ATOMIC_RELAXED, __HIP_MEMORY_SCOPE_AGENT);
      while (__hip_atomic_load(&bar[b * 32], __ATOMIC_RELAXED, __HIP_MEMORY_SCOPE_AGENT) < 4 * gen)
        __builtin_amdgcn_s_sleep(2);
    }
    __syncthreads();
    float T1 = S1, T2 = S2;
#pragma unroll
    for (int sl = 0; sl < 4; ++sl) {
      if (sl == slab) continue;
      T1 += __hip_atomic_load(&part[PIDX(slot, b, sl, 0, tid)],
                              __ATOMIC_RELAXED, __HIP_MEMORY_SCOPE_AGENT);
      T2 += __hip_atomic_load(&part[PIDX(slot, b, sl, 1, tid)],
                              __ATOMIC_RELAXED, __HIP_MEMORY_SCOPE_AGENT);
    }
    const float ci = csinv_l[tid];
    const float vv = 1.0f / (0.5f * fmaf(ci, T1, T2));
    w12[tid] = make_float2(0.5f * vv * ci, vv);
  }

  // ---- finalize: P = E * u_i * v_j * (0.5*csinv_j + 0.5*rinv_i) ----
  __syncthreads();
  float* Pb = &P[((size_t)b * CN + i0 + wv * 16 + q * 4) * CN];
#pragma unroll
  for (int ct = 0; ct < 32; ++ct) {
    const float2 w = w12[ct * 16 + l];
    const float c1 = w.x;
    const float c2 = 0.5f * w.y;
    const v4h ev = eh[ct];
#pragma unroll
    for (int g = 0; g < 4; ++g) {
      const float e = (float)ev[g];
      Pb[(size_t)g * CN + ct * 16 + l] = e * fmaf(u_[g], c1, uri[g] * c2);
    }
  }
#undef PIDX
}

// ---------------------------------------------------------------------------
extern "C" void kernel_launch(void* const* d_in, const int* in_sizes, int n_in,
                              void* d_out, int out_size, void* d_ws, size_t ws_size,
                              hipStream_t stream) {
  const float* in_emb  = (const float*)d_in[0];
  const void*  mask    = d_in[1];
  const float* out_emb = (const float*)d_in[2];
  const float* pad     = (const float*)d_in[3];
  const float* pos     = (const float*)d_in[4];
  const float* W_a     = (const float*)d_in[5];
  const float* W_b     = (const float*)d_in[6];
  const float* w_aff   = (const float*)d_in[7];
  const float* b_aff   = (const float*)d_in[8];
  float* P = (float*)d_out;

  char* ws = (char*)d_ws;
  const size_t MB = 1024 * 1024;
  half_t* A_h  = (half_t*)ws;                         // 8 MB
  half_t* Bm_h = (half_t*)(ws + 8 * MB);              // 8 MB
  float*  part = (float*)(ws + 16 * MB);              // 2 MB
  int*    bar  = (int*)(ws + 20 * MB);                // 8 KB
  int*    flag = (int*)(ws + 20 * MB + 8192);         // 4 B
  half_t* WaF  = (half_t*)(ws + 20 * MB + 12288);     // 64 KB
  half_t* WbF  = (half_t*)(ws + 20 * MB + 12288 + 65536);  // 64 KB

  k0_init<<<dim3(18), dim3(512), 0, stream>>>(mask, bar, flag, W_a, W_b, w_aff, WaF, WbF);
  prep_mfma<0><<<dim3(CB * CN / 128), dim3(256), 0, stream>>>(
      out_emb, pos, nullptr, flag, WaF, A_h);
  prep_mfma<1><<<dim3(CB * CN / 128), dim3(256), 0, stream>>>(
      in_emb, pad, mask, flag, WbF, Bm_h);
  fused_reg<<<dim3(256), dim3(512), 0, stream>>>(A_h, Bm_h, b_aff, P, part, bar);
}